// Round 13
// baseline (642.984 us; speedup 1.0000x reference)
//
#include <hip/hip_runtime.h>
#include <math.h>

#define HC 32          // channels
#define NODE_PER_BLK 8

typedef _Float16 half8 __attribute__((ext_vector_type(8)));
typedef float float4v __attribute__((ext_vector_type(4)));

__device__ __forceinline__ float silu_f(float x) { return x / (1.0f + __expf(-x)); }

__device__ __forceinline__ unsigned int pk2(float a, float b) {
    union { _Float16 h[2]; unsigned int u; } t;
    t.h[0] = (_Float16)a; t.h[1] = (_Float16)b;
    return t.u;
}
__device__ __forceinline__ void unpk2(unsigned int u, float& a, float& b) {
    union { unsigned int u; _Float16 h[2]; } t;
    t.u = u;
    a = (float)t.h[0]; b = (float)t.h[1];
}

// reconstruct 3x3 from compact [i, a01,a02,a12, s00,s01,s02,s11,s12]
__device__ __forceinline__ void recon3(const float* c, float* T) {
    T[0] = c[0] + c[4];  T[1] = c[1] + c[5];  T[2] = c[2] + c[6];
    T[3] = -c[1] + c[5]; T[4] = c[0] + c[7];  T[5] = c[3] + c[8];
    T[6] = -c[2] + c[6]; T[7] = -c[3] + c[8]; T[8] = c[0] - c[4] - c[7];
}

// ---------------- zero cnt ----------------
__global__ __launch_bounds__(1024) void zero_cnt(int* __restrict__ cnt, int N) {
    int i = blockIdx.x * 1024 + threadIdx.x;
    if (i < N) cnt[i] = 0;
}

// ---------------- Kernel T: weights -> f16 MFMA B-fragment layout ----------------
__global__ void prep_weights(const float* __restrict__ Ws0, const float* __restrict__ Ws1,
                             const float* __restrict__ Ws2,
                             _Float16* __restrict__ wf1, _Float16* __restrict__ wf2,
                             _Float16* __restrict__ wf3) {
    int t = blockIdx.x * 256 + threadIdx.x;
    int j = t & 7;
    int lane = (t >> 3) & 63;
    int q = lane >> 4, r = lane & 15;
    if (t < 4096) {                 // Ws0 [32][128]
        int fi = t >> 9, kt = fi >> 1, nt = fi & 1;
        wf1[t] = (_Float16)Ws0[(16 * nt + r) * 128 + 32 * kt + 8 * q + j];
    } else if (t < 6144) {          // Ws1 [64][32]
        int t2 = t - 4096;
        int nt = t2 >> 9;
        wf2[t2] = (_Float16)Ws1[(16 * nt + r) * 32 + 8 * q + j];
    } else if (t < 12288) {         // Ws2 [96][64]
        int t3 = t - 6144;
        int fi = t3 >> 9, kt = fi / 6, nt = fi % 6;
        wf3[t3] = (_Float16)Ws2[(16 * nt + r) * 64 + 32 * kt + 8 * q + j];
    }
}

// ---------------- CSR build: histogram + 3-phase scan + scatter ----------------
__global__ void hist_kernel(const int* __restrict__ dst, int* __restrict__ cnt, int E) {
    int e = blockIdx.x * 256 + threadIdx.x;
    if (e < E) atomicAdd(&cnt[dst[e]], 1);
}

__global__ __launch_bounds__(1024) void scan_a(const int* __restrict__ cnt,
                                               int* __restrict__ bsum, int N) {
    __shared__ int s[1024];
    int i = blockIdx.x * 1024 + threadIdx.x;
    s[threadIdx.x] = (i < N) ? cnt[i] : 0;
    __syncthreads();
    #pragma unroll
    for (int o = 512; o; o >>= 1) {
        if (threadIdx.x < o) s[threadIdx.x] += s[threadIdx.x + o];
        __syncthreads();
    }
    if (threadIdx.x == 0) bsum[blockIdx.x] = s[0];
}

__global__ __launch_bounds__(1024) void scan_b(int* __restrict__ bsum, int nb) {
    __shared__ int s[1024];
    int v = (threadIdx.x < nb) ? bsum[threadIdx.x] : 0;
    s[threadIdx.x] = v;
    __syncthreads();
    #pragma unroll
    for (int o = 1; o < 1024; o <<= 1) {
        int t = (threadIdx.x >= o) ? s[threadIdx.x - o] : 0;
        __syncthreads();
        s[threadIdx.x] += t;
        __syncthreads();
    }
    if (threadIdx.x < nb) bsum[threadIdx.x] = s[threadIdx.x] - v;  // exclusive
}

__global__ __launch_bounds__(1024) void scan_c(const int* __restrict__ cnt,
                                               const int* __restrict__ bsum,
                                               int* __restrict__ off,
                                               int* __restrict__ cursor, int N) {
    __shared__ int s[1024];
    int i = blockIdx.x * 1024 + threadIdx.x;
    int v = (i < N) ? cnt[i] : 0;
    s[threadIdx.x] = v;
    __syncthreads();
    #pragma unroll
    for (int o = 1; o < 1024; o <<= 1) {
        int t = (threadIdx.x >= o) ? s[threadIdx.x - o] : 0;
        __syncthreads();
        s[threadIdx.x] += t;
        __syncthreads();
    }
    int ex = bsum[blockIdx.x] + s[threadIdx.x] - v;
    if (i < N) {
        off[i] = ex;
        cursor[i] = ex;
        if (i == N - 1) off[N] = ex + v;
    }
}

__global__ void scatter_kernel(const int* __restrict__ src, const int* __restrict__ dst,
                               int* __restrict__ cursor, int2* __restrict__ elist, int E) {
    int e = blockIdx.x * 256 + threadIdx.x;
    if (e >= E) return;
    int d = dst[e];
    int pos = atomicAdd(&cursor[d], 1);
    elist[pos] = make_int2(e, src[e]);
}

// ---------------- Kernel A: per-node prep ----------------
__global__ void node_prep(const float* __restrict__ X,
                          const float* __restrict__ lin_w, const float* __restrict__ lin_b,
                          const float* __restrict__ ln_w, const float* __restrict__ ln_b,
                          const float* __restrict__ Wt,
                          _Float16* __restrict__ att_h, unsigned int* __restrict__ comp_g, int N) {
    __shared__ float sX[NODE_PER_BLK][96];
    __shared__ float sC[NODE_PER_BLK][HC * 9];
    int grp = threadIdx.x >> 5;
    int lane = threadIdx.x & 31;
    int n = blockIdx.x * NODE_PER_BLK + grp;
    bool valid = (n < N);

    float m = 0, a01 = 0, a02 = 0, a12 = 0, s00 = 0, s01 = 0, s02 = 0, s11 = 0, s12 = 0;
    float tI = 0, tA = 0, tS = 0, tX = 0;
    if (valid) {
        const float* xp = X + (size_t)n * 288 + lane * 9;
        float t00 = xp[0], t01 = xp[1], t02 = xp[2];
        float t10 = xp[3], t11 = xp[4], t12 = xp[5];
        float t20 = xp[6], t21 = xp[7], t22 = xp[8];
        m = (t00 + t11 + t22) * (1.0f / 3.0f);
        a01 = 0.5f * (t01 - t10); a02 = 0.5f * (t02 - t20); a12 = 0.5f * (t12 - t21);
        s00 = t00 - m; s11 = t11 - m; float s22 = t22 - m;
        s01 = 0.5f * (t01 + t10); s02 = 0.5f * (t02 + t20); s12 = 0.5f * (t12 + t21);
        tI = 3.0f * m * m;
        tA = 2.0f * (a01 * a01 + a02 * a02 + a12 * a12);
        tS = s00 * s00 + s11 * s11 + s22 * s22 + 2.0f * (s01 * s01 + s02 * s02 + s12 * s12);
        tX = tI + tA + tS;
    }
    float lsum = tI + tA + tS;
    #pragma unroll
    for (int o = 16; o; o >>= 1) lsum += __shfl_xor(lsum, o, 32);
    float mu = lsum * (1.0f / 96.0f);
    float d0 = tI - mu, d1 = tA - mu, d2 = tS - mu;
    float lsq = d0 * d0 + d1 * d1 + d2 * d2;
    #pragma unroll
    for (int o = 16; o; o >>= 1) lsq += __shfl_xor(lsq, o, 32);
    float rstd = rsqrtf(lsq * (1.0f / 96.0f) + 1e-5f);
    if (valid) {
        sX[grp][lane]      = d0 * rstd * ln_w[lane]      + ln_b[lane];
        sX[grp][32 + lane] = d1 * rstd * ln_w[32 + lane] + ln_b[32 + lane];
        sX[grp][64 + lane] = d2 * rstd * ln_w[64 + lane] + ln_b[64 + lane];
    }
    __syncthreads();
    if (valid) {
        float acc = lin_b[lane];
        const float* wr = lin_w + lane * 96;
        #pragma unroll
        for (int k = 0; k < 96; k++) acc += wr[k] * sX[grp][k];
        att_h[(size_t)n * 32 + lane] = (_Float16)silu_f(acc);
        float inv = 1.0f / (tX + 1.0f);
        float* cc = &sC[grp][lane * 9];
        cc[0] = m * inv;
        cc[1] = a01 * inv; cc[2] = a02 * inv; cc[3] = a12 * inv;
        cc[4] = s00 * inv; cc[5] = s01 * inv; cc[6] = s02 * inv;
        cc[7] = s11 * inv; cc[8] = s12 * inv;
    }
    __syncthreads();
    if (valid) {
        float o[9];
        #pragma unroll
        for (int c = 0; c < 9; c++) o[c] = 0.0f;
        const float* w0 = Wt + lane * 32;
        const float* w1 = Wt + 1024 + lane * 32;
        const float* w2 = Wt + 2048 + lane * 32;
        #pragma unroll
        for (int h = 0; h < 32; h++) {
            float wi = w0[h], wa = w1[h], ws = w2[h];
            const float* ch = &sC[grp][h * 9];
            o[0] += wi * ch[0];
            o[1] += wa * ch[1]; o[2] += wa * ch[2]; o[3] += wa * ch[3];
            o[4] += ws * ch[4]; o[5] += ws * ch[5]; o[6] += ws * ch[6];
            o[7] += ws * ch[7]; o[8] += ws * ch[8];
        }
        unsigned int* cgp = comp_g + (size_t)n * 160 + lane;
        cgp[0]   = pk2(o[0], o[1]);
        cgp[32]  = pk2(o[2], o[3]);
        cgp[64]  = pk2(o[4], o[5]);
        cgp[96]  = pk2(o[6], o[7]);
        cgp[128] = pk2(o[8], 0.0f);
    }
}

// ---------------- Kernel B: fused f16 MFMA edge MLP ----------------
__device__ __forceinline__ half8 cvt8v(const float* p) {
    float4 v0 = ((const float4*)p)[0];
    float4 v1 = ((const float4*)p)[1];
    half8 h;
    h[0] = (_Float16)v0.x; h[1] = (_Float16)v0.y; h[2] = (_Float16)v0.z; h[3] = (_Float16)v0.w;
    h[4] = (_Float16)v1.x; h[5] = (_Float16)v1.y; h[6] = (_Float16)v1.z; h[7] = (_Float16)v1.w;
    return h;
}

__global__ __launch_bounds__(256) void edge_mfma(
    const _Float16* __restrict__ att_h, const float* __restrict__ rbf,
    const int* __restrict__ src, const int* __restrict__ dst,
    const _Float16* __restrict__ wf1, const _Float16* __restrict__ wf2,
    const _Float16* __restrict__ wf3,
    const float* __restrict__ b0, const float* __restrict__ b1, const float* __restrict__ b2,
    float* __restrict__ e_out, _Float16* __restrict__ e_h, int E) {
    __shared__ _Float16 hbuf[4][16][72];
    int w = threadIdx.x >> 6;
    int lane = threadIdx.x & 63;
    int q = lane >> 4, r = lane & 15;
    int ebase = blockIdx.x * 64 + w * 16;
    int er = min(ebase + r, E - 1);
    int s = src[er], d = dst[er];

    half8 a0 = ((const half8*)(att_h + (size_t)s * 32))[q];
    half8 a1 = ((const half8*)(att_h + (size_t)d * 32))[q];
    half8 a2 = cvt8v(rbf + (size_t)er * 64 + 8 * q);
    half8 a3 = cvt8v(rbf + (size_t)er * 64 + 32 + 8 * q);

    const half8* W1 = (const half8*)wf1;
    float bn0 = b0[r], bn1 = b0[16 + r];
    float4v acc10 = {bn0, bn0, bn0, bn0};
    float4v acc11 = {bn1, bn1, bn1, bn1};
    acc10 = __builtin_amdgcn_mfma_f32_16x16x32_f16(a0, W1[0 * 64 + lane], acc10, 0, 0, 0);
    acc11 = __builtin_amdgcn_mfma_f32_16x16x32_f16(a0, W1[1 * 64 + lane], acc11, 0, 0, 0);
    acc10 = __builtin_amdgcn_mfma_f32_16x16x32_f16(a1, W1[2 * 64 + lane], acc10, 0, 0, 0);
    acc11 = __builtin_amdgcn_mfma_f32_16x16x32_f16(a1, W1[3 * 64 + lane], acc11, 0, 0, 0);
    acc10 = __builtin_amdgcn_mfma_f32_16x16x32_f16(a2, W1[4 * 64 + lane], acc10, 0, 0, 0);
    acc11 = __builtin_amdgcn_mfma_f32_16x16x32_f16(a2, W1[5 * 64 + lane], acc11, 0, 0, 0);
    acc10 = __builtin_amdgcn_mfma_f32_16x16x32_f16(a3, W1[6 * 64 + lane], acc10, 0, 0, 0);
    acc11 = __builtin_amdgcn_mfma_f32_16x16x32_f16(a3, W1[7 * 64 + lane], acc11, 0, 0, 0);
    #pragma unroll
    for (int reg = 0; reg < 4; reg++) {
        hbuf[w][4 * q + reg][r]      = (_Float16)silu_f(acc10[reg]);
        hbuf[w][4 * q + reg][16 + r] = (_Float16)silu_f(acc11[reg]);
    }

    half8 ah1 = *(const half8*)&hbuf[w][r][8 * q];
    const half8* W2 = (const half8*)wf2;
    float4v acc2[4];
    #pragma unroll
    for (int nt = 0; nt < 4; nt++) {
        float bb = b1[16 * nt + r];
        acc2[nt] = (float4v){bb, bb, bb, bb};
        acc2[nt] = __builtin_amdgcn_mfma_f32_16x16x32_f16(ah1, W2[nt * 64 + lane], acc2[nt], 0, 0, 0);
    }
    #pragma unroll
    for (int nt = 0; nt < 4; nt++) {
        #pragma unroll
        for (int reg = 0; reg < 4; reg++) {
            hbuf[w][4 * q + reg][16 * nt + r] = (_Float16)silu_f(acc2[nt][reg]);
        }
    }

    half8 ah20 = *(const half8*)&hbuf[w][r][8 * q];
    half8 ah21 = *(const half8*)&hbuf[w][r][32 + 8 * q];
    const half8* W3 = (const half8*)wf3;
    float4v acc3[6];
    #pragma unroll
    for (int nt = 0; nt < 6; nt++) {
        float bb = b2[16 * nt + r];
        acc3[nt] = (float4v){bb, bb, bb, bb};
        acc3[nt] = __builtin_amdgcn_mfma_f32_16x16x32_f16(ah20, W3[nt * 64 + lane], acc3[nt], 0, 0, 0);
        acc3[nt] = __builtin_amdgcn_mfma_f32_16x16x32_f16(ah21, W3[(6 + nt) * 64 + lane], acc3[nt], 0, 0, 0);
    }
    if (e_h != nullptr) {
        #pragma unroll
        for (int nt = 0; nt < 6; nt++) {
            #pragma unroll
            for (int reg = 0; reg < 4; reg++) {
                int ee = ebase + 4 * q + reg;
                if (ee < E) {
                    float v = silu_f(acc3[nt][reg]);
                    e_out[(size_t)ee * 96 + 16 * nt + r] = v;
                    e_h[(size_t)ee * 96 + 16 * nt + r] = (_Float16)v;
                }
            }
        }
    } else {
        #pragma unroll
        for (int nt = 0; nt < 6; nt++) {
            #pragma unroll
            for (int reg = 0; reg < 4; reg++) {
                int ee = ebase + 4 * q + reg;
                if (ee < E) e_out[(size_t)ee * 96 + 16 * nt + r] = silu_f(acc3[nt][reg]);
            }
        }
    }
}

// ---------------- Kernel C: fused gather + per-node finalize ----------------
// round-9 structure; EH=true reads the f16 e-copy (half the random-read bytes),
// EH=false reads f32 e_out (fallback when ws_size can't hold e_h).
template<bool EH>
__global__ __launch_bounds__(256) void gather_final(
    const float* __restrict__ X, const unsigned int* __restrict__ comp_g,
    const float* __restrict__ e_f, const _Float16* __restrict__ e_hp,
    const int* __restrict__ off, const int2* __restrict__ elist,
    const float* __restrict__ Wt, float* __restrict__ Xout, int N) {
    __shared__ float sB[NODE_PER_BLK][HC * 9];
    int grp = threadIdx.x >> 5;
    int lane = threadIdx.x & 31;
    int n = blockIdx.x * NODE_PER_BLK + grp;
    bool valid = (n < N);

    float cm[9];
    #pragma unroll
    for (int c = 0; c < 9; c++) cm[c] = 0.0f;

    if (valid) {
        int start = off[n], end = off[n + 1];
        int idx = start;
        // 4-deep unrolled: batch-issue independent loads before any FMA
        for (; idx + 4 <= end; idx += 4) {
            int ex[4], sx[4];
            #pragma unroll
            for (int u = 0; u < 4; u++) {
                int2 es = elist[idx + u];
                ex[u] = es.x; sx[u] = es.y;
            }
            float ev[4][3];
            unsigned int cg[4][5];
            #pragma unroll
            for (int u = 0; u < 4; u++) {
                if (EH) {
                    const _Float16* ep = e_hp + (size_t)ex[u] * 96 + lane * 3;
                    ev[u][0] = (float)ep[0]; ev[u][1] = (float)ep[1]; ev[u][2] = (float)ep[2];
                } else {
                    const float* ep = e_f + (size_t)ex[u] * 96 + lane * 3;
                    ev[u][0] = ep[0]; ev[u][1] = ep[1]; ev[u][2] = ep[2];
                }
                const unsigned int* cp = comp_g + (size_t)sx[u] * 160 + lane;
                cg[u][0] = cp[0]; cg[u][1] = cp[32]; cg[u][2] = cp[64];
                cg[u][3] = cp[96]; cg[u][4] = cp[128];
            }
            #pragma unroll
            for (int u = 0; u < 4; u++) {
                float c0, c1, c2, c3, c4, c5, c6, c7, c8, cz;
                unpk2(cg[u][0], c0, c1);
                unpk2(cg[u][1], c2, c3);
                unpk2(cg[u][2], c4, c5);
                unpk2(cg[u][3], c6, c7);
                unpk2(cg[u][4], c8, cz);
                float e0 = ev[u][0], e1 = ev[u][1], e2 = ev[u][2];
                cm[0] += e0 * c0;
                cm[1] += e1 * c1; cm[2] += e1 * c2; cm[3] += e1 * c3;
                cm[4] += e2 * c4; cm[5] += e2 * c5; cm[6] += e2 * c6;
                cm[7] += e2 * c7; cm[8] += e2 * c8;
            }
        }
        for (; idx < end; idx++) {
            int2 es = elist[idx];
            float e0, e1, e2;
            if (EH) {
                const _Float16* ep = e_hp + (size_t)es.x * 96 + lane * 3;
                e0 = (float)ep[0]; e1 = (float)ep[1]; e2 = (float)ep[2];
            } else {
                const float* ep = e_f + (size_t)es.x * 96 + lane * 3;
                e0 = ep[0]; e1 = ep[1]; e2 = ep[2];
            }
            const unsigned int* cp = comp_g + (size_t)es.y * 160 + lane;
            float c0, c1, c2, c3, c4, c5, c6, c7, c8, cz;
            unpk2(cp[0], c0, c1);
            unpk2(cp[32], c2, c3);
            unpk2(cp[64], c4, c5);
            unpk2(cp[96], c6, c7);
            unpk2(cp[128], c8, cz);
            cm[0] += e0 * c0;
            cm[1] += e1 * c1; cm[2] += e1 * c2; cm[3] += e1 * c3;
            cm[4] += e2 * c4; cm[5] += e2 * c5; cm[6] += e2 * c6;
            cm[7] += e2 * c7; cm[8] += e2 * c8;
        }
    }

    if (valid) {
        float cy[9], cz;
        const unsigned int* cgn = comp_g + (size_t)n * 160 + lane;
        unpk2(cgn[0], cy[0], cy[1]);
        unpk2(cgn[32], cy[2], cy[3]);
        unpk2(cgn[64], cy[4], cy[5]);
        unpk2(cgn[96], cy[6], cy[7]);
        unpk2(cgn[128], cy[8], cz);
        float M[9], Y[9];
        recon3(cm, M);
        recon3(cy, Y);
        float B[9];
        #pragma unroll
        for (int i = 0; i < 3; i++) {
            #pragma unroll
            for (int j = 0; j < 3; j++) {
                float acc = 0.0f;
                #pragma unroll
                for (int k = 0; k < 3; k++)
                    acc += M[i * 3 + k] * Y[k * 3 + j] + Y[i * 3 + k] * M[k * 3 + j];
                B[i * 3 + j] = acc;
            }
        }
        float mB = (B[0] + B[4] + B[8]) * (1.0f / 3.0f);
        float tn = 1.0f;
        #pragma unroll
        for (int i = 0; i < 9; i++) tn += B[i] * B[i];
        float itn = 1.0f / tn;
        float* bb = &sB[grp][lane * 9];
        bb[0] = mB * itn;
        bb[1] = 0.5f * (B[1] - B[3]) * itn;
        bb[2] = 0.5f * (B[2] - B[6]) * itn;
        bb[3] = 0.5f * (B[5] - B[7]) * itn;
        bb[4] = (B[0] - mB) * itn;
        bb[5] = 0.5f * (B[1] + B[3]) * itn;
        bb[6] = 0.5f * (B[2] + B[6]) * itn;
        bb[7] = (B[4] - mB) * itn;
        bb[8] = 0.5f * (B[5] + B[7]) * itn;
    }
    __syncthreads();
    if (valid) {
        float o[9];
        #pragma unroll
        for (int c = 0; c < 9; c++) o[c] = 0.0f;
        const float* w3 = Wt + 3 * 1024 + lane * 32;
        const float* w4 = Wt + 4 * 1024 + lane * 32;
        const float* w5 = Wt + 5 * 1024 + lane * 32;
        #pragma unroll
        for (int h = 0; h < 32; h++) {
            float wi = w3[h], wa = w4[h], ws = w5[h];
            const float* ch = &sB[grp][h * 9];
            o[0] += wi * ch[0];
            o[1] += wa * ch[1]; o[2] += wa * ch[2]; o[3] += wa * ch[3];
            o[4] += ws * ch[4]; o[5] += ws * ch[5]; o[6] += ws * ch[6];
            o[7] += ws * ch[7]; o[8] += ws * ch[8];
        }
        float D[9];
        recon3(o, D);
        const float* xp = X + (size_t)n * 288 + lane * 9;
        float xv[9];
        float tt = 0.0f;
        #pragma unroll
        for (int i = 0; i < 9; i++) { xv[i] = xp[i]; tt += xv[i] * xv[i]; }
        float inv = 1.0f / (tt + 1.0f);
        float P[9];
        #pragma unroll
        for (int i = 0; i < 3; i++) {
            #pragma unroll
            for (int j = 0; j < 3; j++) {
                float acc = 0.0f;
                #pragma unroll
                for (int k = 0; k < 3; k++) acc += D[i * 3 + k] * D[k * 3 + j];
                P[i * 3 + j] = acc;
            }
        }
        float* op = Xout + (size_t)n * 288 + lane * 9;
        #pragma unroll
        for (int i = 0; i < 9; i++) op[i] = xv[i] * inv + D[i] + P[i];
    }
}

extern "C" void kernel_launch(void* const* d_in, const int* in_sizes, int n_in,
                              void* d_out, int out_size, void* d_ws, size_t ws_size,
                              hipStream_t stream) {
    const float* X = (const float*)d_in[0];
    const float* rbf = (const float*)d_in[1];
    const int* src = (const int*)d_in[3];
    const int* dst = (const int*)d_in[4];
    const float* Ws0 = (const float*)d_in[5];
    const float* b0 = (const float*)d_in[6];
    const float* Ws1 = (const float*)d_in[7];
    const float* b1 = (const float*)d_in[8];
    const float* Ws2 = (const float*)d_in[9];
    const float* b2 = (const float*)d_in[10];
    const float* Wt = (const float*)d_in[11];
    const float* ln_w = (const float*)d_in[12];
    const float* ln_b = (const float*)d_in[13];
    const float* lin_w = (const float*)d_in[14];
    const float* lin_b = (const float*)d_in[15];

    int N = in_sizes[0] / 288;  // X: [N,32,3,3]
    int E = in_sizes[1] / 64;   // rbf: [E,64]

    float* Xout = (float*)d_out;
    float* e_out = (float*)d_out + (size_t)N * 288;

    // workspace layout
    _Float16* att_h = (_Float16*)d_ws;                    // N*32 halfs
    unsigned int* comp_g = (unsigned int*)(att_h + (size_t)N * 32);  // N*160 uints
    _Float16* wf1 = (_Float16*)(comp_g + (size_t)N * 160);
    _Float16* wf2 = wf1 + 4096;
    _Float16* wf3 = wf2 + 2048;
    int* cnt = (int*)(wf3 + 6144);                        // N
    int* off = cnt + N;                                   // N+1
    int* cursor = off + N + 1;                            // N (+1 pad)
    int* bsum = cursor + N + 1;                           // nb (+pad)
    int2* elist = (int2*)(bsum + 1026);                   // E int2 (8B-aligned)
    _Float16* e_h = (_Float16*)(elist + E);               // E*96 halfs (optional)

    // ws_size guard: only enable the f16-e path if the workspace can hold e_h.
    size_t needed = (size_t)((char*)(e_h + (size_t)E * 96) - (char*)d_ws);
    bool use_eh = (needed <= ws_size);

    int nb = (N + 1023) / 1024;

    zero_cnt<<<nb, 1024, 0, stream>>>(cnt, N);
    prep_weights<<<48, 256, 0, stream>>>(Ws0, Ws1, Ws2, wf1, wf2, wf3);
    node_prep<<<(N + NODE_PER_BLK - 1) / NODE_PER_BLK, 256, 0, stream>>>(
        X, lin_w, lin_b, ln_w, ln_b, Wt, att_h, comp_g, N);
    hist_kernel<<<(E + 255) / 256, 256, 0, stream>>>(dst, cnt, E);
    scan_a<<<nb, 1024, 0, stream>>>(cnt, bsum, N);
    scan_b<<<1, 1024, 0, stream>>>(bsum, nb);
    scan_c<<<nb, 1024, 0, stream>>>(cnt, bsum, off, cursor, N);
    scatter_kernel<<<(E + 255) / 256, 256, 0, stream>>>(src, dst, cursor, elist, E);
    edge_mfma<<<(E + 63) / 64, 256, 0, stream>>>(
        att_h, rbf, src, dst, wf1, wf2, wf3, b0, b1, b2,
        e_out, use_eh ? e_h : nullptr, E);
    if (use_eh) {
        gather_final<true><<<(N + NODE_PER_BLK - 1) / NODE_PER_BLK, 256, 0, stream>>>(
            X, comp_g, e_out, e_h, off, elist, Wt, Xout, N);
    } else {
        gather_final<false><<<(N + NODE_PER_BLK - 1) / NODE_PER_BLK, 256, 0, stream>>>(
            X, comp_g, e_out, e_h, off, elist, Wt, Xout, N);
    }
}

// Round 14
// 574.156 us; speedup vs baseline: 1.1199x; 1.1199x over previous
//
#include <hip/hip_runtime.h>
#include <math.h>

#define HC 32          // channels
#define NODE_PER_BLK 8

typedef _Float16 half8 __attribute__((ext_vector_type(8)));
typedef float float4v __attribute__((ext_vector_type(4)));

__device__ __forceinline__ float silu_f(float x) { return x / (1.0f + __expf(-x)); }

__device__ __forceinline__ unsigned int pk2(float a, float b) {
    union { _Float16 h[2]; unsigned int u; } t;
    t.h[0] = (_Float16)a; t.h[1] = (_Float16)b;
    return t.u;
}
__device__ __forceinline__ void unpk2(unsigned int u, float& a, float& b) {
    union { unsigned int u; _Float16 h[2]; } t;
    t.u = u;
    a = (float)t.h[0]; b = (float)t.h[1];
}

// reconstruct 3x3 from compact [i, a01,a02,a12, s00,s01,s02,s11,s12]
__device__ __forceinline__ void recon3(const float* c, float* T) {
    T[0] = c[0] + c[4];  T[1] = c[1] + c[5];  T[2] = c[2] + c[6];
    T[3] = -c[1] + c[5]; T[4] = c[0] + c[7];  T[5] = c[3] + c[8];
    T[6] = -c[2] + c[6]; T[7] = -c[3] + c[8]; T[8] = c[0] - c[4] - c[7];
}

// ---------------- zero cnt ----------------
__global__ __launch_bounds__(1024) void zero_cnt(int* __restrict__ cnt, int N) {
    int i = blockIdx.x * 1024 + threadIdx.x;
    if (i < N) cnt[i] = 0;
}

// ---------------- Kernel T: weights -> f16 MFMA B-fragment layout ----------------
__global__ void prep_weights(const float* __restrict__ Ws0, const float* __restrict__ Ws1,
                             const float* __restrict__ Ws2,
                             _Float16* __restrict__ wf1, _Float16* __restrict__ wf2,
                             _Float16* __restrict__ wf3) {
    int t = blockIdx.x * 256 + threadIdx.x;
    int j = t & 7;
    int lane = (t >> 3) & 63;
    int q = lane >> 4, r = lane & 15;
    if (t < 4096) {                 // Ws0 [32][128]
        int fi = t >> 9, kt = fi >> 1, nt = fi & 1;
        wf1[t] = (_Float16)Ws0[(16 * nt + r) * 128 + 32 * kt + 8 * q + j];
    } else if (t < 6144) {          // Ws1 [64][32]
        int t2 = t - 4096;
        int nt = t2 >> 9;
        wf2[t2] = (_Float16)Ws1[(16 * nt + r) * 32 + 8 * q + j];
    } else if (t < 12288) {         // Ws2 [96][64]
        int t3 = t - 6144;
        int fi = t3 >> 9, kt = fi / 6, nt = fi % 6;
        wf3[t3] = (_Float16)Ws2[(16 * nt + r) * 64 + 32 * kt + 8 * q + j];
    }
}

// ---------------- CSR build: histogram + 3-phase scan + scatter ----------------
__global__ void hist_kernel(const int* __restrict__ dst, int* __restrict__ cnt, int E) {
    int e = blockIdx.x * 256 + threadIdx.x;
    if (e < E) atomicAdd(&cnt[dst[e]], 1);
}

__global__ __launch_bounds__(1024) void scan_a(const int* __restrict__ cnt,
                                               int* __restrict__ bsum, int N) {
    __shared__ int s[1024];
    int i = blockIdx.x * 1024 + threadIdx.x;
    s[threadIdx.x] = (i < N) ? cnt[i] : 0;
    __syncthreads();
    #pragma unroll
    for (int o = 512; o; o >>= 1) {
        if (threadIdx.x < o) s[threadIdx.x] += s[threadIdx.x + o];
        __syncthreads();
    }
    if (threadIdx.x == 0) bsum[blockIdx.x] = s[0];
}

__global__ __launch_bounds__(1024) void scan_b(int* __restrict__ bsum, int nb) {
    __shared__ int s[1024];
    int v = (threadIdx.x < nb) ? bsum[threadIdx.x] : 0;
    s[threadIdx.x] = v;
    __syncthreads();
    #pragma unroll
    for (int o = 1; o < 1024; o <<= 1) {
        int t = (threadIdx.x >= o) ? s[threadIdx.x - o] : 0;
        __syncthreads();
        s[threadIdx.x] += t;
        __syncthreads();
    }
    if (threadIdx.x < nb) bsum[threadIdx.x] = s[threadIdx.x] - v;  // exclusive
}

__global__ __launch_bounds__(1024) void scan_c(const int* __restrict__ cnt,
                                               const int* __restrict__ bsum,
                                               int* __restrict__ off,
                                               int* __restrict__ cursor, int N) {
    __shared__ int s[1024];
    int i = blockIdx.x * 1024 + threadIdx.x;
    int v = (i < N) ? cnt[i] : 0;
    s[threadIdx.x] = v;
    __syncthreads();
    #pragma unroll
    for (int o = 1; o < 1024; o <<= 1) {
        int t = (threadIdx.x >= o) ? s[threadIdx.x - o] : 0;
        __syncthreads();
        s[threadIdx.x] += t;
        __syncthreads();
    }
    int ex = bsum[blockIdx.x] + s[threadIdx.x] - v;
    if (i < N) {
        off[i] = ex;
        cursor[i] = ex;
        if (i == N - 1) off[N] = ex + v;
    }
}

__global__ void scatter_kernel(const int* __restrict__ src, const int* __restrict__ dst,
                               int* __restrict__ cursor, int2* __restrict__ elist, int E) {
    int e = blockIdx.x * 256 + threadIdx.x;
    if (e >= E) return;
    int d = dst[e];
    int pos = atomicAdd(&cursor[d], 1);
    elist[pos] = make_int2(e, src[e]);
}

// ---------------- Kernel A: per-node prep ----------------
__global__ void node_prep(const float* __restrict__ X,
                          const float* __restrict__ lin_w, const float* __restrict__ lin_b,
                          const float* __restrict__ ln_w, const float* __restrict__ ln_b,
                          const float* __restrict__ Wt,
                          _Float16* __restrict__ att_h, unsigned int* __restrict__ comp_g, int N) {
    __shared__ float sX[NODE_PER_BLK][96];
    __shared__ float sC[NODE_PER_BLK][HC * 9];
    int grp = threadIdx.x >> 5;
    int lane = threadIdx.x & 31;
    int n = blockIdx.x * NODE_PER_BLK + grp;
    bool valid = (n < N);

    float m = 0, a01 = 0, a02 = 0, a12 = 0, s00 = 0, s01 = 0, s02 = 0, s11 = 0, s12 = 0;
    float tI = 0, tA = 0, tS = 0, tX = 0;
    if (valid) {
        const float* xp = X + (size_t)n * 288 + lane * 9;
        float t00 = xp[0], t01 = xp[1], t02 = xp[2];
        float t10 = xp[3], t11 = xp[4], t12 = xp[5];
        float t20 = xp[6], t21 = xp[7], t22 = xp[8];
        m = (t00 + t11 + t22) * (1.0f / 3.0f);
        a01 = 0.5f * (t01 - t10); a02 = 0.5f * (t02 - t20); a12 = 0.5f * (t12 - t21);
        s00 = t00 - m; s11 = t11 - m; float s22 = t22 - m;
        s01 = 0.5f * (t01 + t10); s02 = 0.5f * (t02 + t20); s12 = 0.5f * (t12 + t21);
        tI = 3.0f * m * m;
        tA = 2.0f * (a01 * a01 + a02 * a02 + a12 * a12);
        tS = s00 * s00 + s11 * s11 + s22 * s22 + 2.0f * (s01 * s01 + s02 * s02 + s12 * s12);
        tX = tI + tA + tS;
    }
    float lsum = tI + tA + tS;
    #pragma unroll
    for (int o = 16; o; o >>= 1) lsum += __shfl_xor(lsum, o, 32);
    float mu = lsum * (1.0f / 96.0f);
    float d0 = tI - mu, d1 = tA - mu, d2 = tS - mu;
    float lsq = d0 * d0 + d1 * d1 + d2 * d2;
    #pragma unroll
    for (int o = 16; o; o >>= 1) lsq += __shfl_xor(lsq, o, 32);
    float rstd = rsqrtf(lsq * (1.0f / 96.0f) + 1e-5f);
    if (valid) {
        sX[grp][lane]      = d0 * rstd * ln_w[lane]      + ln_b[lane];
        sX[grp][32 + lane] = d1 * rstd * ln_w[32 + lane] + ln_b[32 + lane];
        sX[grp][64 + lane] = d2 * rstd * ln_w[64 + lane] + ln_b[64 + lane];
    }
    __syncthreads();
    if (valid) {
        float acc = lin_b[lane];
        const float* wr = lin_w + lane * 96;
        #pragma unroll
        for (int k = 0; k < 96; k++) acc += wr[k] * sX[grp][k];
        att_h[(size_t)n * 32 + lane] = (_Float16)silu_f(acc);
        float inv = 1.0f / (tX + 1.0f);
        float* cc = &sC[grp][lane * 9];
        cc[0] = m * inv;
        cc[1] = a01 * inv; cc[2] = a02 * inv; cc[3] = a12 * inv;
        cc[4] = s00 * inv; cc[5] = s01 * inv; cc[6] = s02 * inv;
        cc[7] = s11 * inv; cc[8] = s12 * inv;
    }
    __syncthreads();
    if (valid) {
        float o[9];
        #pragma unroll
        for (int c = 0; c < 9; c++) o[c] = 0.0f;
        const float* w0 = Wt + lane * 32;
        const float* w1 = Wt + 1024 + lane * 32;
        const float* w2 = Wt + 2048 + lane * 32;
        #pragma unroll
        for (int h = 0; h < 32; h++) {
            float wi = w0[h], wa = w1[h], ws = w2[h];
            const float* ch = &sC[grp][h * 9];
            o[0] += wi * ch[0];
            o[1] += wa * ch[1]; o[2] += wa * ch[2]; o[3] += wa * ch[3];
            o[4] += ws * ch[4]; o[5] += ws * ch[5]; o[6] += ws * ch[6];
            o[7] += ws * ch[7]; o[8] += ws * ch[8];
        }
        unsigned int* cgp = comp_g + (size_t)n * 160 + lane;
        cgp[0]   = pk2(o[0], o[1]);
        cgp[32]  = pk2(o[2], o[3]);
        cgp[64]  = pk2(o[4], o[5]);
        cgp[96]  = pk2(o[6], o[7]);
        cgp[128] = pk2(o[8], 0.0f);
    }
}

// ---------------- Kernel B: fused f16 MFMA edge MLP ----------------
__device__ __forceinline__ half8 cvt8v(const float* p) {
    float4 v0 = ((const float4*)p)[0];
    float4 v1 = ((const float4*)p)[1];
    half8 h;
    h[0] = (_Float16)v0.x; h[1] = (_Float16)v0.y; h[2] = (_Float16)v0.z; h[3] = (_Float16)v0.w;
    h[4] = (_Float16)v1.x; h[5] = (_Float16)v1.y; h[6] = (_Float16)v1.z; h[7] = (_Float16)v1.w;
    return h;
}

__global__ __launch_bounds__(256) void edge_mfma(
    const _Float16* __restrict__ att_h, const float* __restrict__ rbf,
    const int* __restrict__ src, const int* __restrict__ dst,
    const _Float16* __restrict__ wf1, const _Float16* __restrict__ wf2,
    const _Float16* __restrict__ wf3,
    const float* __restrict__ b0, const float* __restrict__ b1, const float* __restrict__ b2,
    float* __restrict__ e_out, int E) {
    __shared__ _Float16 hbuf[4][16][72];
    int w = threadIdx.x >> 6;
    int lane = threadIdx.x & 63;
    int q = lane >> 4, r = lane & 15;
    int ebase = blockIdx.x * 64 + w * 16;
    int er = min(ebase + r, E - 1);
    int s = src[er], d = dst[er];

    half8 a0 = ((const half8*)(att_h + (size_t)s * 32))[q];
    half8 a1 = ((const half8*)(att_h + (size_t)d * 32))[q];
    half8 a2 = cvt8v(rbf + (size_t)er * 64 + 8 * q);
    half8 a3 = cvt8v(rbf + (size_t)er * 64 + 32 + 8 * q);

    const half8* W1 = (const half8*)wf1;
    float bn0 = b0[r], bn1 = b0[16 + r];
    float4v acc10 = {bn0, bn0, bn0, bn0};
    float4v acc11 = {bn1, bn1, bn1, bn1};
    acc10 = __builtin_amdgcn_mfma_f32_16x16x32_f16(a0, W1[0 * 64 + lane], acc10, 0, 0, 0);
    acc11 = __builtin_amdgcn_mfma_f32_16x16x32_f16(a0, W1[1 * 64 + lane], acc11, 0, 0, 0);
    acc10 = __builtin_amdgcn_mfma_f32_16x16x32_f16(a1, W1[2 * 64 + lane], acc10, 0, 0, 0);
    acc11 = __builtin_amdgcn_mfma_f32_16x16x32_f16(a1, W1[3 * 64 + lane], acc11, 0, 0, 0);
    acc10 = __builtin_amdgcn_mfma_f32_16x16x32_f16(a2, W1[4 * 64 + lane], acc10, 0, 0, 0);
    acc11 = __builtin_amdgcn_mfma_f32_16x16x32_f16(a2, W1[5 * 64 + lane], acc11, 0, 0, 0);
    acc10 = __builtin_amdgcn_mfma_f32_16x16x32_f16(a3, W1[6 * 64 + lane], acc10, 0, 0, 0);
    acc11 = __builtin_amdgcn_mfma_f32_16x16x32_f16(a3, W1[7 * 64 + lane], acc11, 0, 0, 0);
    #pragma unroll
    for (int reg = 0; reg < 4; reg++) {
        hbuf[w][4 * q + reg][r]      = (_Float16)silu_f(acc10[reg]);
        hbuf[w][4 * q + reg][16 + r] = (_Float16)silu_f(acc11[reg]);
    }

    half8 ah1 = *(const half8*)&hbuf[w][r][8 * q];
    const half8* W2 = (const half8*)wf2;
    float4v acc2[4];
    #pragma unroll
    for (int nt = 0; nt < 4; nt++) {
        float bb = b1[16 * nt + r];
        acc2[nt] = (float4v){bb, bb, bb, bb};
        acc2[nt] = __builtin_amdgcn_mfma_f32_16x16x32_f16(ah1, W2[nt * 64 + lane], acc2[nt], 0, 0, 0);
    }
    #pragma unroll
    for (int nt = 0; nt < 4; nt++) {
        #pragma unroll
        for (int reg = 0; reg < 4; reg++) {
            hbuf[w][4 * q + reg][16 * nt + r] = (_Float16)silu_f(acc2[nt][reg]);
        }
    }

    half8 ah20 = *(const half8*)&hbuf[w][r][8 * q];
    half8 ah21 = *(const half8*)&hbuf[w][r][32 + 8 * q];
    const half8* W3 = (const half8*)wf3;
    float4v acc3[6];
    #pragma unroll
    for (int nt = 0; nt < 6; nt++) {
        float bb = b2[16 * nt + r];
        acc3[nt] = (float4v){bb, bb, bb, bb};
        acc3[nt] = __builtin_amdgcn_mfma_f32_16x16x32_f16(ah20, W3[nt * 64 + lane], acc3[nt], 0, 0, 0);
        acc3[nt] = __builtin_amdgcn_mfma_f32_16x16x32_f16(ah21, W3[(6 + nt) * 64 + lane], acc3[nt], 0, 0, 0);
    }
    #pragma unroll
    for (int nt = 0; nt < 6; nt++) {
        #pragma unroll
        for (int reg = 0; reg < 4; reg++) {
            int ee = ebase + 4 * q + reg;
            if (ee < E) e_out[(size_t)ee * 96 + 16 * nt + r] = silu_f(acc3[nt][reg]);
        }
    }
}

// ---------------- Kernel C: fused gather + per-node finalize ----------------
__global__ __launch_bounds__(256) void gather_final(
    const float* __restrict__ X, const unsigned int* __restrict__ comp_g,
    const float* __restrict__ e_out,
    const int* __restrict__ off, const int2* __restrict__ elist,
    const float* __restrict__ Wt, float* __restrict__ Xout, int N) {
    __shared__ float sB[NODE_PER_BLK][HC * 9];
    int grp = threadIdx.x >> 5;
    int lane = threadIdx.x & 31;
    int n = blockIdx.x * NODE_PER_BLK + grp;
    bool valid = (n < N);

    float cm[9];
    #pragma unroll
    for (int c = 0; c < 9; c++) cm[c] = 0.0f;

    if (valid) {
        int start = off[n], end = off[n + 1];
        int idx = start;
        // 4-deep unrolled: batch-issue 24 independent loads before any FMA
        for (; idx + 4 <= end; idx += 4) {
            int ex[4], sx[4];
            #pragma unroll
            for (int u = 0; u < 4; u++) {
                int2 es = elist[idx + u];
                ex[u] = es.x; sx[u] = es.y;
            }
            float ev[4][3];
            unsigned int cg[4][5];
            #pragma unroll
            for (int u = 0; u < 4; u++) {
                const float* ep = e_out + (size_t)ex[u] * 96 + lane * 3;
                ev[u][0] = __builtin_nontemporal_load(ep);
                ev[u][1] = __builtin_nontemporal_load(ep + 1);
                ev[u][2] = __builtin_nontemporal_load(ep + 2);
                const unsigned int* cp = comp_g + (size_t)sx[u] * 160 + lane;
                cg[u][0] = cp[0]; cg[u][1] = cp[32]; cg[u][2] = cp[64];
                cg[u][3] = cp[96]; cg[u][4] = cp[128];
            }
            #pragma unroll
            for (int u = 0; u < 4; u++) {
                float c0, c1, c2, c3, c4, c5, c6, c7, c8, cz;
                unpk2(cg[u][0], c0, c1);
                unpk2(cg[u][1], c2, c3);
                unpk2(cg[u][2], c4, c5);
                unpk2(cg[u][3], c6, c7);
                unpk2(cg[u][4], c8, cz);
                float e0 = ev[u][0], e1 = ev[u][1], e2 = ev[u][2];
                cm[0] += e0 * c0;
                cm[1] += e1 * c1; cm[2] += e1 * c2; cm[3] += e1 * c3;
                cm[4] += e2 * c4; cm[5] += e2 * c5; cm[6] += e2 * c6;
                cm[7] += e2 * c7; cm[8] += e2 * c8;
            }
        }
        for (; idx < end; idx++) {
            int2 es = elist[idx];
            const float* ep = e_out + (size_t)es.x * 96 + lane * 3;
            float e0 = __builtin_nontemporal_load(ep);
            float e1 = __builtin_nontemporal_load(ep + 1);
            float e2 = __builtin_nontemporal_load(ep + 2);
            const unsigned int* cp = comp_g + (size_t)es.y * 160 + lane;
            float c0, c1, c2, c3, c4, c5, c6, c7, c8, cz;
            unpk2(cp[0], c0, c1);
            unpk2(cp[32], c2, c3);
            unpk2(cp[64], c4, c5);
            unpk2(cp[96], c6, c7);
            unpk2(cp[128], c8, cz);
            cm[0] += e0 * c0;
            cm[1] += e1 * c1; cm[2] += e1 * c2; cm[3] += e1 * c3;
            cm[4] += e2 * c4; cm[5] += e2 * c5; cm[6] += e2 * c6;
            cm[7] += e2 * c7; cm[8] += e2 * c8;
        }
    }

    if (valid) {
        float cy[9], cz;
        const unsigned int* cgn = comp_g + (size_t)n * 160 + lane;
        unpk2(cgn[0], cy[0], cy[1]);
        unpk2(cgn[32], cy[2], cy[3]);
        unpk2(cgn[64], cy[4], cy[5]);
        unpk2(cgn[96], cy[6], cy[7]);
        unpk2(cgn[128], cy[8], cz);
        float M[9], Y[9];
        recon3(cm, M);
        recon3(cy, Y);
        float B[9];
        #pragma unroll
        for (int i = 0; i < 3; i++) {
            #pragma unroll
            for (int j = 0; j < 3; j++) {
                float acc = 0.0f;
                #pragma unroll
                for (int k = 0; k < 3; k++)
                    acc += M[i * 3 + k] * Y[k * 3 + j] + Y[i * 3 + k] * M[k * 3 + j];
                B[i * 3 + j] = acc;
            }
        }
        float mB = (B[0] + B[4] + B[8]) * (1.0f / 3.0f);
        float tn = 1.0f;
        #pragma unroll
        for (int i = 0; i < 9; i++) tn += B[i] * B[i];
        float itn = 1.0f / tn;
        float* bb = &sB[grp][lane * 9];
        bb[0] = mB * itn;
        bb[1] = 0.5f * (B[1] - B[3]) * itn;
        bb[2] = 0.5f * (B[2] - B[6]) * itn;
        bb[3] = 0.5f * (B[5] - B[7]) * itn;
        bb[4] = (B[0] - mB) * itn;
        bb[5] = 0.5f * (B[1] + B[3]) * itn;
        bb[6] = 0.5f * (B[2] + B[6]) * itn;
        bb[7] = (B[4] - mB) * itn;
        bb[8] = 0.5f * (B[5] + B[7]) * itn;
    }
    __syncthreads();
    if (valid) {
        float o[9];
        #pragma unroll
        for (int c = 0; c < 9; c++) o[c] = 0.0f;
        const float* w3 = Wt + 3 * 1024 + lane * 32;
        const float* w4 = Wt + 4 * 1024 + lane * 32;
        const float* w5 = Wt + 5 * 1024 + lane * 32;
        #pragma unroll
        for (int h = 0; h < 32; h++) {
            float wi = w3[h], wa = w4[h], ws = w5[h];
            const float* ch = &sB[grp][h * 9];
            o[0] += wi * ch[0];
            o[1] += wa * ch[1]; o[2] += wa * ch[2]; o[3] += wa * ch[3];
            o[4] += ws * ch[4]; o[5] += ws * ch[5]; o[6] += ws * ch[6];
            o[7] += ws * ch[7]; o[8] += ws * ch[8];
        }
        float D[9];
        recon3(o, D);
        const float* xp = X + (size_t)n * 288 + lane * 9;
        float xv[9];
        float tt = 0.0f;
        #pragma unroll
        for (int i = 0; i < 9; i++) { xv[i] = xp[i]; tt += xv[i] * xv[i]; }
        float inv = 1.0f / (tt + 1.0f);
        float P[9];
        #pragma unroll
        for (int i = 0; i < 3; i++) {
            #pragma unroll
            for (int j = 0; j < 3; j++) {
                float acc = 0.0f;
                #pragma unroll
                for (int k = 0; k < 3; k++) acc += D[i * 3 + k] * D[k * 3 + j];
                P[i * 3 + j] = acc;
            }
        }
        float* op = Xout + (size_t)n * 288 + lane * 9;
        #pragma unroll
        for (int i = 0; i < 9; i++) op[i] = xv[i] * inv + D[i] + P[i];
    }
}

extern "C" void kernel_launch(void* const* d_in, const int* in_sizes, int n_in,
                              void* d_out, int out_size, void* d_ws, size_t ws_size,
                              hipStream_t stream) {
    const float* X = (const float*)d_in[0];
    const float* rbf = (const float*)d_in[1];
    const int* src = (const int*)d_in[3];
    const int* dst = (const int*)d_in[4];
    const float* Ws0 = (const float*)d_in[5];
    const float* b0 = (const float*)d_in[6];
    const float* Ws1 = (const float*)d_in[7];
    const float* b1 = (const float*)d_in[8];
    const float* Ws2 = (const float*)d_in[9];
    const float* b2 = (const float*)d_in[10];
    const float* Wt = (const float*)d_in[11];
    const float* ln_w = (const float*)d_in[12];
    const float* ln_b = (const float*)d_in[13];
    const float* lin_w = (const float*)d_in[14];
    const float* lin_b = (const float*)d_in[15];

    int N = in_sizes[0] / 288;  // X: [N,32,3,3]
    int E = in_sizes[1] / 64;   // rbf: [E,64]

    float* Xout = (float*)d_out;
    float* e_out = (float*)d_out + (size_t)N * 288;

    // workspace layout
    _Float16* att_h = (_Float16*)d_ws;                    // N*32 halfs
    unsigned int* comp_g = (unsigned int*)(att_h + (size_t)N * 32);  // N*160 uints
    _Float16* wf1 = (_Float16*)(comp_g + (size_t)N * 160);
    _Float16* wf2 = wf1 + 4096;
    _Float16* wf3 = wf2 + 2048;
    int* cnt = (int*)(wf3 + 6144);                        // N
    int* off = cnt + N;                                   // N+1
    int* cursor = off + N + 1;                            // N (+1 pad)
    int* bsum = cursor + N + 1;                           // nb (+pad)
    int2* elist = (int2*)(bsum + 1026);                   // E int2 (8B-aligned)

    int nb = (N + 1023) / 1024;

    zero_cnt<<<nb, 1024, 0, stream>>>(cnt, N);
    prep_weights<<<48, 256, 0, stream>>>(Ws0, Ws1, Ws2, wf1, wf2, wf3);
    node_prep<<<(N + NODE_PER_BLK - 1) / NODE_PER_BLK, 256, 0, stream>>>(
        X, lin_w, lin_b, ln_w, ln_b, Wt, att_h, comp_g, N);
    hist_kernel<<<(E + 255) / 256, 256, 0, stream>>>(dst, cnt, E);
    scan_a<<<nb, 1024, 0, stream>>>(cnt, bsum, N);
    scan_b<<<1, 1024, 0, stream>>>(bsum, nb);
    scan_c<<<nb, 1024, 0, stream>>>(cnt, bsum, off, cursor, N);
    scatter_kernel<<<(E + 255) / 256, 256, 0, stream>>>(src, dst, cursor, elist, E);
    edge_mfma<<<(E + 63) / 64, 256, 0, stream>>>(
        att_h, rbf, src, dst, wf1, wf2, wf3, b0, b1, b2, e_out, E);
    gather_final<<<(N + NODE_PER_BLK - 1) / NODE_PER_BLK, 256, 0, stream>>>(
        X, comp_g, e_out, off, elist, Wt, Xout, N);
}